// Round 13
// baseline (222.547 us; speedup 1.0000x reference)
//
#include <hip/hip_runtime.h>
#include <hip/hip_bf16.h>
#include <stdint.h>
#include <stddef.h>

#define B_ 2
#define T_ 2048
#define C_ 1024
#define H_ 16
#define D_ 64
#define M_ (B_*T_)   // 4096

typedef __attribute__((ext_vector_type(8))) short short8;
typedef __attribute__((ext_vector_type(4))) float f32x4;
typedef __attribute__((ext_vector_type(16))) float f32x16;
typedef __attribute__((ext_vector_type(4))) unsigned int u32x4;

__device__ __forceinline__ unsigned short f2bf(float f) {
    unsigned u = __float_as_uint(f);
    unsigned r = 0x7FFFu + ((u >> 16) & 1u);
    return (unsigned short)((u + r) >> 16);
}

__device__ __forceinline__ unsigned cvtpk_bf16(float lo, float hi) {
    unsigned r;
    asm("v_cvt_pk_bf16_f32 %0, %1, %2" : "=v"(r) : "v"(lo), "v"(hi));
    return r;
}

// guaranteed single-instruction 2^x
__device__ __forceinline__ float fexp2(float x) {
    float r;
    asm("v_exp_f32 %0, %1" : "=v"(r) : "v"(x));
    return r;
}

// v_permlane32_swap_b32: a = [a_lo | b_lo], b = [a_hi | b_hi]
__device__ __forceinline__ void plswap(unsigned &a, unsigned &b) {
    asm("v_permlane32_swap_b32 %0, %1" : "+v"(a), "+v"(b));
}

__device__ __forceinline__ float xhalf_max(float v) {
    float a = v, b = v;
    asm("" : "+v"(b));
    asm("v_permlane32_swap_b32 %0, %1" : "+v"(a), "+v"(b));
    return fmaxf(a, b);
}
__device__ __forceinline__ float xhalf_sum(float v) {
    float a = v, b = v;
    asm("" : "+v"(b));
    asm("v_permlane32_swap_b32 %0, %1" : "+v"(a), "+v"(b));
    return a + b;
}

__device__ __forceinline__ void gload16(const void* g, void* l) {
    __builtin_amdgcn_global_load_lds(
        (__attribute__((address_space(1))) void*)g,
        (__attribute__((address_space(3))) void*)l,
        16, 0, 0);
}

// ---------------- fp32 -> bf16 conversion: all 5 tensors, one launch ----------------
__global__ void cvt_all(const float* __restrict__ x,  const float* __restrict__ wk,
                        const float* __restrict__ wq, const float* __restrict__ wv,
                        const float* __restrict__ wo,
                        unsigned short* __restrict__ xb,  unsigned short* __restrict__ wkb,
                        unsigned short* __restrict__ wqb, unsigned short* __restrict__ wvb,
                        unsigned short* __restrict__ wob) {
    int idx = (blockIdx.x * blockDim.x + threadIdx.x) * 4;
    const float* in; unsigned short* out; int off;
    if      (idx < (4<<20)) { in = x;  out = xb;  off = idx; }
    else if (idx < (5<<20)) { in = wk; out = wkb; off = idx - (4<<20); }
    else if (idx < (6<<20)) { in = wq; out = wqb; off = idx - (5<<20); }
    else if (idx < (7<<20)) { in = wv; out = wvb; off = idx - (6<<20); }
    else                    { in = wo; out = wob; off = idx - (7<<20); }
    float4 v = *reinterpret_cast<const float4*>(in + off);
    ushort4 o;
    o.x = f2bf(v.x); o.y = f2bf(v.y); o.z = f2bf(v.z); o.w = f2bf(v.w);
    *reinterpret_cast<ushort4*>(out + off) = o;
}

// ---------------- fused QKV projection GEMM (R9-verified: BK=32) ----------------
__global__ __launch_bounds__(256) void gemm_qkv(
    const unsigned short* __restrict__ A,
    const unsigned short* __restrict__ W0,
    const unsigned short* __restrict__ W1,
    const unsigned short* __restrict__ W2,
    const float* __restrict__ b0,
    const float* __restrict__ b1,
    const float* __restrict__ b2,
    unsigned short* __restrict__ o0,   // k
    unsigned short* __restrict__ o1,   // q (pre-scaled by LOG2E/32)
    unsigned short* __restrict__ o2)   // vt
{
    __shared__ unsigned short As[128*32];
    __shared__ unsigned short Bs[128*32];
    int which = blockIdx.x >> 8;
    int bx = blockIdx.x & 255;
    int bm = bx >> 3, bn = bx & 7;
    const unsigned short* W = (which==0) ? W0 : ((which==1) ? W1 : W2);
    const float* bias = (which==0) ? b0 : ((which==1) ? b1 : b2);

    int tid = threadIdx.x;
    int lane = tid & 63;
    int fr = lane & 15, fq = lane >> 4;
    int wid = tid >> 6;
    int wr = wid >> 1, wc = wid & 1;

    int srow = tid >> 2;            // 0..63
    int scol = (tid & 3) << 3;      // 0,8,16,24
    const unsigned short* Ab = A + (size_t)(bm*128 + srow) * C_ + scol;
    const unsigned short* Wb = W + (size_t)(bn*128 + srow) * C_ + scol;

    f32x4 acc[4][4] = {};

    for (int kt = 0; kt < C_/32; ++kt) {
        int ko = kt*32;
        gload16(Ab + ko,            &As[tid*8]);
        gload16(Ab + 64*C_ + ko,    &As[2048 + tid*8]);
        gload16(Wb + ko,            &Bs[tid*8]);
        gload16(Wb + 64*C_ + ko,    &Bs[2048 + tid*8]);
        __syncthreads();
        short8 af[4], bfr[4];
        #pragma unroll
        for (int i = 0; i < 4; ++i) {
            af[i]  = *reinterpret_cast<const short8*>(&As[(wr*64 + i*16 + fr)*32 + fq*8]);
            bfr[i] = *reinterpret_cast<const short8*>(&Bs[(wc*64 + i*16 + fr)*32 + fq*8]);
        }
        #pragma unroll
        for (int i = 0; i < 4; ++i)
            #pragma unroll
            for (int j = 0; j < 4; ++j)
                acc[i][j] = __builtin_amdgcn_mfma_f32_16x16x32_bf16(af[i], bfr[j], acc[i][j], 0, 0, 0);
        __syncthreads();
    }

    float sc = (which == 1) ? 0.045084220f : 1.0f;
    int mbase = bm*128 + wr*64;
    int nbase = bn*128 + wc*64;
    #pragma unroll
    for (int j = 0; j < 4; ++j) {
        int col = nbase + j*16 + fr;
        float bv = bias[col];
        int h = col >> 6, d = col & 63;
        #pragma unroll
        for (int i = 0; i < 4; ++i) {
            int r0 = mbase + i*16 + fq*4;
            #pragma unroll
            for (int r = 0; r < 4; ++r) {
                float v = (acc[i][j][r] + bv) * sc;
                int m = r0 + r;
                int b = m >> 11, t = m & (T_-1);
                unsigned short hv = f2bf(v);
                if (which == 2)
                    o2[((size_t)(b*H_ + h)*D_ + d)*T_ + t] = hv;
                else {
                    unsigned short* o = (which==0) ? o0 : o1;
                    o[((size_t)(b*H_ + h)*T_ + t)*D_ + d] = hv;
                }
            }
        }
    }
}

// ---------------- output projection GEMM (R9-verified: BK=32) ----------------
__global__ __launch_bounds__(256) void gemm_out(
    const unsigned short* __restrict__ A,   // y bf16 [M_][C_]
    const unsigned short* __restrict__ W,   // Wo bf16 [C_][C_]
    const float* __restrict__ bias,
    float* __restrict__ out)
{
    __shared__ unsigned short As[128*32];
    __shared__ unsigned short Bs[128*32];
    int bx = blockIdx.x;
    int bm = bx >> 3, bn = bx & 7;

    int tid = threadIdx.x;
    int lane = tid & 63;
    int fr = lane & 15, fq = lane >> 4;
    int wid = tid >> 6;
    int wr = wid >> 1, wc = wid & 1;

    int srow = tid >> 2;
    int scol = (tid & 3) << 3;
    const unsigned short* Ab = A + (size_t)(bm*128 + srow) * C_ + scol;
    const unsigned short* Wb = W + (size_t)(bn*128 + srow) * C_ + scol;

    f32x4 acc[4][4] = {};

    for (int kt = 0; kt < C_/32; ++kt) {
        int ko = kt*32;
        gload16(Ab + ko,            &As[tid*8]);
        gload16(Ab + 64*C_ + ko,    &As[2048 + tid*8]);
        gload16(Wb + ko,            &Bs[tid*8]);
        gload16(Wb + 64*C_ + ko,    &Bs[2048 + tid*8]);
        __syncthreads();
        short8 af[4], bfr[4];
        #pragma unroll
        for (int i = 0; i < 4; ++i) {
            af[i]  = *reinterpret_cast<const short8*>(&As[(wr*64 + i*16 + fr)*32 + fq*8]);
            bfr[i] = *reinterpret_cast<const short8*>(&Bs[(wc*64 + i*16 + fr)*32 + fq*8]);
        }
        #pragma unroll
        for (int i = 0; i < 4; ++i)
            #pragma unroll
            for (int j = 0; j < 4; ++j)
                acc[i][j] = __builtin_amdgcn_mfma_f32_16x16x32_bf16(af[i], bfr[j], acc[i][j], 0, 0, 0);
        __syncthreads();
    }

    int mbase = bm*128 + wr*64;
    int nbase = bn*128 + wc*64;
    #pragma unroll
    for (int j = 0; j < 4; ++j) {
        int col = nbase + j*16 + fr;
        float bv = bias[col];
        #pragma unroll
        for (int i = 0; i < 4; ++i) {
            int r0 = mbase + i*16 + fq*4;
            #pragma unroll
            for (int r = 0; r < 4; ++r)
                out[(size_t)(r0 + r)*C_ + col] = acc[i][j][r] + bv;
        }
    }
}

// ---------------- flash attention: 4-way KV split, 4 blocks/CU ----------------
// Block = 4 waves sharing one 64-q-row group (2 chains of 32 rows). Each wave owns a
// quarter of the KV range in KVBLK=32 tiles. Single-buffered 32 KB staging; 4-way
// LDS merge (R5-verified math) run once per chain. Subtile math = R11-verified.
__device__ __forceinline__ void attn_subtile(
    const short8 (&kf)[4], const short8 (&qf)[4],
    const short8 (&vlo)[2], const short8 (&vhi)[2],
    bool diag, int l31, int hi,
    f32x16& o0, f32x16& o1, float& m_, float& l_)
{
    f32x16 a0 = {};
    __builtin_amdgcn_s_setprio(1);
    a0 = __builtin_amdgcn_mfma_f32_32x32x16_bf16(kf[0], qf[0], a0, 0, 0, 0);
    a0 = __builtin_amdgcn_mfma_f32_32x32x16_bf16(kf[1], qf[1], a0, 0, 0, 0);
    a0 = __builtin_amdgcn_mfma_f32_32x32x16_bf16(kf[2], qf[2], a0, 0, 0, 0);
    a0 = __builtin_amdgcn_mfma_f32_32x32x16_bf16(kf[3], qf[3], a0, 0, 0, 0);
    __builtin_amdgcn_s_setprio(0);

    if (diag) {
        #pragma unroll
        for (int r = 0; r < 16; ++r) {
            int kvl = (r&3) + 8*(r>>2) + 4*hi;
            if (kvl > l31) a0[r] = -1e30f;
        }
    }

    float x0 = fmaxf(a0[0], a0[1]),   x1 = fmaxf(a0[2], a0[3]);
    float x2 = fmaxf(a0[4], a0[5]),   x3 = fmaxf(a0[6], a0[7]);
    float x4 = fmaxf(a0[8], a0[9]),   x5 = fmaxf(a0[10], a0[11]);
    float x6 = fmaxf(a0[12], a0[13]), x7 = fmaxf(a0[14], a0[15]);
    float y0 = fmaxf(x0, x1), y1 = fmaxf(x2, x3), y2 = fmaxf(x4, x5), y3 = fmaxf(x6, x7);
    float pm = fmaxf(fmaxf(y0, y1), fmaxf(y2, y3));
    pm = xhalf_max(pm);

    if (!__all(pm - m_ <= 8.0f)) {
        float mn = fmaxf(m_, pm);
        float alpha = fexp2(m_ - mn);
        l_ *= alpha;
        m_ = mn;
        #pragma unroll
        for (int r = 0; r < 16; ++r) {
            int row = (r&3) + 8*(r>>2) + 4*hi;
            float ar = __shfl(alpha, row);
            o0[r] *= ar;
            o1[r] *= ar;
        }
    }

    #pragma unroll
    for (int r = 0; r < 16; ++r)
        a0[r] = fexp2(a0[r] - m_);
    float s0 = a0[0]+a0[1],  s1 = a0[2]+a0[3],  s2 = a0[4]+a0[5],   s3 = a0[6]+a0[7];
    float s4 = a0[8]+a0[9],  s5 = a0[10]+a0[11], s6 = a0[12]+a0[13], s7 = a0[14]+a0[15];
    float u0 = s0+s1, u1 = s2+s3, u2 = s4+s5, u3 = s6+s7;
    float rs = (u0+u1) + (u2+u3);
    rs = xhalf_sum(rs);
    l_ += rs;

    unsigned pk_[8];
    #pragma unroll
    for (int jj = 0; jj < 8; ++jj)
        pk_[jj] = cvtpk_bf16(a0[2*jj], a0[2*jj+1]);

    #pragma unroll
    for (int kb = 0; kb < 2; ++kb) {
        unsigned fx = pk_[4*kb+0], fz = pk_[4*kb+2];
        unsigned fy = pk_[4*kb+1], fw = pk_[4*kb+3];
        plswap(fx, fz);
        plswap(fy, fw);
        u32x4 wv;
        wv.x = fx; wv.y = fy; wv.z = fz; wv.w = fw;
        short8 pfrag = __builtin_bit_cast(short8, wv);
        __builtin_amdgcn_s_setprio(1);
        o0 = __builtin_amdgcn_mfma_f32_32x32x16_bf16(pfrag, vlo[kb], o0, 0, 0, 0);
        o1 = __builtin_amdgcn_mfma_f32_32x32x16_bf16(pfrag, vhi[kb], o1, 0, 0, 0);
        __builtin_amdgcn_s_setprio(0);
    }
}

__global__ __launch_bounds__(256, 4) void flash_attn(
    const unsigned short* __restrict__ q,
    const unsigned short* __restrict__ k,
    const unsigned short* __restrict__ vt,
    unsigned short* __restrict__ y)
{
    // 36 KB LDS: staging [8 tiles][2048 shorts] (32 KB) aliased with merge overlay
    __shared__ __align__(16) char LDSRAW[36864];
    unsigned short (*ST16)[2048] = reinterpret_cast<unsigned short(*)[2048]>(LDSRAW);
    float* oP = reinterpret_cast<float*>(LDSRAW);   // [4 splits][32 rows][68]
    float* mP = oP + 4*32*68;                       // [4][32]
    float* lP = mP + 128;                           // [4][32]

    int tid = threadIdx.x, lane = tid & 63, w = tid >> 6;
    int l31 = lane & 31, hi = lane >> 5;
    int bid = blockIdx.x;

    // complementary work pairing: c(j)+c(31-j) = 17 for co-resident halves
    int half = bid >> 9;
    int idx  = bid & 511;
    int bh   = (idx & 7)*4 + ((idx >> 3) & 3);   // 4 heads per XCD
    int jidx = idx >> 5;                          // 0..15
    int j    = half ? jidx : (31 - jidx);         // 64-row q-group, heavy first

    const unsigned short* kp = k  + (size_t)bh*T_*D_;
    const unsigned short* vp = vt + (size_t)bh*D_*T_;
    int b = bh >> 4, h = bh & 15;

    int rowbase = j*64;
    const unsigned short* qp = q + ((size_t)bh*T_ + rowbase) * D_;

    short8 qf0[4], qf1[4];
    #pragma unroll
    for (int dk = 0; dk < 4; ++dk) {
        qf0[dk] = *reinterpret_cast<const short8*>(qp + (size_t)l31*D_        + dk*16 + hi*8);
        qf1[dk] = *reinterpret_cast<const short8*>(qp + (size_t)(32 + l31)*D_ + dk*16 + hi*8);
    }

    f32x16 o00 = {}, o01 = {}, o10 = {}, o11 = {};
    float m0 = -1e30f, l0 = 0.f, m1 = -1e30f, l1 = 0.f;

    int cc   = (j + 2) >> 1;     // ceil((2j+2)/4): tiles per wave
    int lim0 = 2*j, lim1 = 2*j + 1;

    // stage iteration ii: 4 K tiles + 4 V tiles (one per wave), 8 gload16/thread
    #define STAGE(ii)                                                                 \
    {                                                                                 \
        int c2 = tid;                                                                 \
        int krow = c2 >> 3;                                                           \
        int kslot = (c2 & 7) ^ (krow & 7);                                            \
        int vrow = c2 >> 2;                                                           \
        int vslot = (c2 & 3) ^ (vrow & 3);                                            \
        _Pragma("unroll")                                                             \
        for (int ww = 0; ww < 4; ++ww) {                                              \
            int tw = ww*cc + (ii);                                                    \
            gload16(kp + ((size_t)(tw*32 + krow))*D_ + kslot*8, &ST16[ww][c2*8]);     \
            gload16(vp + (size_t)vrow*T_ + tw*32 + vslot*8,     &ST16[4+ww][c2*8]);   \
        }                                                                             \
    }

    for (int i = 0; i < cc; ++i) {
        STAGE(i);
        __syncthreads();
        int t = w*cc + i;
        if (t <= lim1) {
            const unsigned short* Kl = ST16[w];
            const unsigned short* Vl = ST16[4 + w];
            short8 kf[4];
            #pragma unroll
            for (int dk = 0; dk < 4; ++dk)
                kf[dk] = *reinterpret_cast<const short8*>(
                    Kl + l31*64 + ((((dk<<1)|hi)) ^ (l31 & 7))*8);
            short8 vlo[2], vhi[2];
            #pragma unroll
            for (int kb = 0; kb < 2; ++kb) {
                int sl = ((((kb<<1)|hi)) ^ (l31 & 3)) * 8;
                vlo[kb] = *reinterpret_cast<const short8*>(Vl + l31*32 + sl);
                vhi[kb] = *reinterpret_cast<const short8*>(Vl + (32 + l31)*32 + sl);
            }
            if (t <= lim0)
                attn_subtile(kf, qf0, vlo, vhi, t == lim0, l31, hi, o00, o01, m0, l0);
            attn_subtile(kf, qf1, vlo, vhi, t == lim1, l31, hi, o10, o11, m1, l1);
        }
        __syncthreads();
    }
    #undef STAGE

    // ---- 4-way merge per chain (R5-verified math), overlay aliases staging ----
    #define MERGE(oA, oB, mv, lv, rowoff)                                             \
    {                                                                                 \
        __syncthreads();                                                              \
        _Pragma("unroll")                                                             \
        for (int rr = 0; rr < 16; ++rr) {                                             \
            int crow = (rr&3) + 8*(rr>>2) + 4*hi;                                     \
            oP[(w*32 + crow)*68 + l31]      = oA[rr];                                 \
            oP[(w*32 + crow)*68 + 32 + l31] = oB[rr];                                 \
        }                                                                             \
        if (!hi) { mP[w*32 + l31] = mv; lP[w*32 + l31] = lv; }                        \
        __syncthreads();                                                              \
        {                                                                             \
            int qr = tid >> 3;                                                        \
            int dc = tid & 7;                                                         \
            float mm0 = mP[qr], mm1 = mP[32+qr], mm2 = mP[64+qr], mm3 = mP[96+qr];    \
            float ms = fmaxf(fmaxf(mm0, mm1), fmaxf(mm2, mm3));                       \
            float a0_ = fexp2(mm0 - ms), a1_ = fexp2(mm1 - ms);                       \
            float a2_ = fexp2(mm2 - ms), a3_ = fexp2(mm3 - ms);                       \
            float ls = a0_*lP[qr] + a1_*lP[32+qr] + a2_*lP[64+qr] + a3_*lP[96+qr];    \
            float inv = 1.0f / ls;                                                    \
            unsigned short yv[8];                                                     \
            _Pragma("unroll")                                                         \
            for (int e = 0; e < 8; ++e) {                                             \
                float acc = a0_ * oP[(0*32+qr)*68 + dc*8 + e]                         \
                          + a1_ * oP[(1*32+qr)*68 + dc*8 + e]                         \
                          + a2_ * oP[(2*32+qr)*68 + dc*8 + e]                         \
                          + a3_ * oP[(3*32+qr)*68 + dc*8 + e];                        \
                yv[e] = f2bf(acc * inv);                                              \
            }                                                                         \
            int trow = rowbase + (rowoff) + qr;                                       \
            size_t base = ((size_t)(b*T_ + trow))*C_ + h*64 + dc*8;                   \
            *reinterpret_cast<short8*>(y + base) = *reinterpret_cast<short8*>(yv);    \
        }                                                                             \
    }

    MERGE(o00, o01, m0, l0, 0);
    MERGE(o10, o11, m1, l1, 32);
    #undef MERGE
}

extern "C" void kernel_launch(void* const* d_in, const int* in_sizes, int n_in,
                              void* d_out, int out_size, void* d_ws, size_t ws_size,
                              hipStream_t stream) {
    const float* x  = (const float*)d_in[0];
    const float* Wk = (const float*)d_in[1];
    const float* bk = (const float*)d_in[2];
    const float* Wq = (const float*)d_in[3];
    const float* bq = (const float*)d_in[4];
    const float* Wv = (const float*)d_in[5];
    const float* bv = (const float*)d_in[6];
    const float* Wo = (const float*)d_in[7];
    const float* bo = (const float*)d_in[8];
    float* out = (float*)d_out;

    char* ws = (char*)d_ws;
    unsigned short* xb  = (unsigned short*)(ws);                    // 8MB
    unsigned short* wkb = (unsigned short*)(ws + ((size_t)8  << 20));
    unsigned short* wqb = (unsigned short*)(ws + ((size_t)10 << 20));
    unsigned short* wvb = (unsigned short*)(ws + ((size_t)12 << 20));
    unsigned short* wob = (unsigned short*)(ws + ((size_t)14 << 20));
    unsigned short* qb  = (unsigned short*)(ws + ((size_t)16 << 20)); // [B,H,T,D]
    unsigned short* kb  = (unsigned short*)(ws + ((size_t)24 << 20)); // [B,H,T,D]
    unsigned short* vtb = (unsigned short*)(ws + ((size_t)32 << 20)); // [B,H,D,T]
    unsigned short* yb  = (unsigned short*)(ws + ((size_t)40 << 20)); // [B*T,C]

    cvt_all<<<dim3(8192), dim3(256), 0, stream>>>(
        x, Wk, Wq, Wv, Wo, xb, wkb, wqb, wvb, wob);

    gemm_qkv<<<dim3(768), dim3(256), 0, stream>>>(xb, wkb, wqb, wvb, bk, bq, bv, kb, qb, vtb);

    flash_attn<<<dim3(1024), dim3(256), 0, stream>>>(qb, kb, vtb, yb);

    gemm_out<<<dim3(256), dim3(256), 0, stream>>>(yb, wob, bo, out);
}

// Round 14
// 119.372 us; speedup vs baseline: 1.8643x; 1.8643x over previous
//
#include <hip/hip_runtime.h>
#include <hip/hip_bf16.h>
#include <stdint.h>
#include <stddef.h>

#define B_ 2
#define T_ 2048
#define C_ 1024
#define H_ 16
#define D_ 64
#define M_ (B_*T_)   // 4096

typedef __attribute__((ext_vector_type(8))) short short8;
typedef __attribute__((ext_vector_type(4))) float f32x4;
typedef __attribute__((ext_vector_type(16))) float f32x16;
typedef __attribute__((ext_vector_type(4))) unsigned int u32x4;

__device__ __forceinline__ unsigned short f2bf(float f) {
    unsigned u = __float_as_uint(f);
    unsigned r = 0x7FFFu + ((u >> 16) & 1u);
    return (unsigned short)((u + r) >> 16);
}

__device__ __forceinline__ unsigned cvtpk_bf16(float lo, float hi) {
    unsigned r;
    asm("v_cvt_pk_bf16_f32 %0, %1, %2" : "=v"(r) : "v"(lo), "v"(hi));
    return r;
}

// guaranteed single-instruction 2^x
__device__ __forceinline__ float fexp2(float x) {
    float r;
    asm("v_exp_f32 %0, %1" : "=v"(r) : "v"(x));
    return r;
}

// v_permlane32_swap_b32: a = [a_lo | b_lo], b = [a_hi | b_hi]
__device__ __forceinline__ void plswap(unsigned &a, unsigned &b) {
    asm("v_permlane32_swap_b32 %0, %1" : "+v"(a), "+v"(b));
}

__device__ __forceinline__ float xhalf_max(float v) {
    float a = v, b = v;
    asm("" : "+v"(b));
    asm("v_permlane32_swap_b32 %0, %1" : "+v"(a), "+v"(b));
    return fmaxf(a, b);
}
__device__ __forceinline__ float xhalf_sum(float v) {
    float a = v, b = v;
    asm("" : "+v"(b));
    asm("v_permlane32_swap_b32 %0, %1" : "+v"(a), "+v"(b));
    return a + b;
}

__device__ __forceinline__ void gload16(const void* g, void* l) {
    __builtin_amdgcn_global_load_lds(
        (__attribute__((address_space(1))) void*)g,
        (__attribute__((address_space(3))) void*)l,
        16, 0, 0);
}

// ---------------- fp32 -> bf16 conversion: all 5 tensors, one launch ----------------
__global__ void cvt_all(const float* __restrict__ x,  const float* __restrict__ wk,
                        const float* __restrict__ wq, const float* __restrict__ wv,
                        const float* __restrict__ wo,
                        unsigned short* __restrict__ xb,  unsigned short* __restrict__ wkb,
                        unsigned short* __restrict__ wqb, unsigned short* __restrict__ wvb,
                        unsigned short* __restrict__ wob) {
    int idx = (blockIdx.x * blockDim.x + threadIdx.x) * 4;
    const float* in; unsigned short* out; int off;
    if      (idx < (4<<20)) { in = x;  out = xb;  off = idx; }
    else if (idx < (5<<20)) { in = wk; out = wkb; off = idx - (4<<20); }
    else if (idx < (6<<20)) { in = wq; out = wqb; off = idx - (5<<20); }
    else if (idx < (7<<20)) { in = wv; out = wvb; off = idx - (6<<20); }
    else                    { in = wo; out = wob; off = idx - (7<<20); }
    float4 v = *reinterpret_cast<const float4*>(in + off);
    ushort4 o;
    o.x = f2bf(v.x); o.y = f2bf(v.y); o.z = f2bf(v.z); o.w = f2bf(v.w);
    *reinterpret_cast<ushort4*>(out + off) = o;
}

// ---------------- fused QKV projection GEMM: 64x128 tile, BK=32 ----------------
// which 0 -> K [B,H,T,D], which 1 -> Q*scale [B,H,T,D], which 2 -> V^T [B,H,D,T]
__global__ __launch_bounds__(256, 6) void gemm_qkv(
    const unsigned short* __restrict__ A,
    const unsigned short* __restrict__ W0,
    const unsigned short* __restrict__ W1,
    const unsigned short* __restrict__ W2,
    const float* __restrict__ b0,
    const float* __restrict__ b1,
    const float* __restrict__ b2,
    unsigned short* __restrict__ o0,   // k
    unsigned short* __restrict__ o1,   // q (pre-scaled by LOG2E/32)
    unsigned short* __restrict__ o2)   // vt
{
    __shared__ unsigned short As[64*32];    // 4 KB
    __shared__ unsigned short Bs[128*32];   // 8 KB
    int which = blockIdx.x >> 9;
    int bx = blockIdx.x & 511;
    int bm = bx >> 3, bn = bx & 7;          // bm 0..63 (64 rows), bn 0..7 (128 cols)
    const unsigned short* W = (which==0) ? W0 : ((which==1) ? W1 : W2);
    const float* bias = (which==0) ? b0 : ((which==1) ? b1 : b2);

    int tid = threadIdx.x;
    int lane = tid & 63;
    int fr = lane & 15, fq = lane >> 4;
    int wid = tid >> 6;
    int wr = wid >> 1, wc = wid & 1;

    int arow = tid >> 2;            // 0..63
    int acol = (tid & 3) << 3;      // 0,8,16,24
    const unsigned short* Ab = A + (size_t)(bm*64 + arow) * C_ + acol;
    const unsigned short* Wb = W + (size_t)(bn*128 + arow) * C_ + acol;

    f32x4 acc[2][4] = {};

    for (int kt = 0; kt < C_/32; ++kt) {
        int ko = kt*32;
        gload16(Ab + ko,            &As[tid*8]);
        gload16(Wb + ko,            &Bs[tid*8]);
        gload16(Wb + 64*C_ + ko,    &Bs[2048 + tid*8]);
        __syncthreads();
        short8 af[2], bfr[4];
        #pragma unroll
        for (int i = 0; i < 2; ++i)
            af[i]  = *reinterpret_cast<const short8*>(&As[(wr*32 + i*16 + fr)*32 + fq*8]);
        #pragma unroll
        for (int j = 0; j < 4; ++j)
            bfr[j] = *reinterpret_cast<const short8*>(&Bs[(wc*64 + j*16 + fr)*32 + fq*8]);
        #pragma unroll
        for (int i = 0; i < 2; ++i)
            #pragma unroll
            for (int j = 0; j < 4; ++j)
                acc[i][j] = __builtin_amdgcn_mfma_f32_16x16x32_bf16(af[i], bfr[j], acc[i][j], 0, 0, 0);
        __syncthreads();
    }

    // Q: fold 1/sqrt(C)=1/32 AND log2(e) so QK^T lands in log2 domain
    float sc = (which == 1) ? 0.045084220f : 1.0f;
    int mbase = bm*64 + wr*32;
    int nbase = bn*128 + wc*64;
    #pragma unroll
    for (int j = 0; j < 4; ++j) {
        int col = nbase + j*16 + fr;
        float bv = bias[col];
        int h = col >> 6, d = col & 63;
        #pragma unroll
        for (int i = 0; i < 2; ++i) {
            int r0 = mbase + i*16 + fq*4;
            #pragma unroll
            for (int r = 0; r < 4; ++r) {
                float v = (acc[i][j][r] + bv) * sc;
                int m = r0 + r;
                int b = m >> 11, t = m & (T_-1);
                unsigned short hv = f2bf(v);
                if (which == 2)
                    o2[((size_t)(b*H_ + h)*D_ + d)*T_ + t] = hv;
                else {
                    unsigned short* o = (which==0) ? o0 : o1;
                    o[((size_t)(b*H_ + h)*T_ + t)*D_ + d] = hv;
                }
            }
        }
    }
}

// ---------------- output projection GEMM: 64x128 tile, BK=32 ----------------
__global__ __launch_bounds__(256, 6) void gemm_out(
    const unsigned short* __restrict__ A,   // y bf16 [M_][C_]
    const unsigned short* __restrict__ W,   // Wo bf16 [C_][C_]
    const float* __restrict__ bias,
    float* __restrict__ out)
{
    __shared__ unsigned short As[64*32];
    __shared__ unsigned short Bs[128*32];
    int bx = blockIdx.x;
    int bm = bx >> 3, bn = bx & 7;

    int tid = threadIdx.x;
    int lane = tid & 63;
    int fr = lane & 15, fq = lane >> 4;
    int wid = tid >> 6;
    int wr = wid >> 1, wc = wid & 1;

    int arow = tid >> 2;
    int acol = (tid & 3) << 3;
    const unsigned short* Ab = A + (size_t)(bm*64 + arow) * C_ + acol;
    const unsigned short* Wb = W + (size_t)(bn*128 + arow) * C_ + acol;

    f32x4 acc[2][4] = {};

    for (int kt = 0; kt < C_/32; ++kt) {
        int ko = kt*32;
        gload16(Ab + ko,            &As[tid*8]);
        gload16(Wb + ko,            &Bs[tid*8]);
        gload16(Wb + 64*C_ + ko,    &Bs[2048 + tid*8]);
        __syncthreads();
        short8 af[2], bfr[4];
        #pragma unroll
        for (int i = 0; i < 2; ++i)
            af[i]  = *reinterpret_cast<const short8*>(&As[(wr*32 + i*16 + fr)*32 + fq*8]);
        #pragma unroll
        for (int j = 0; j < 4; ++j)
            bfr[j] = *reinterpret_cast<const short8*>(&Bs[(wc*64 + j*16 + fr)*32 + fq*8]);
        #pragma unroll
        for (int i = 0; i < 2; ++i)
            #pragma unroll
            for (int j = 0; j < 4; ++j)
                acc[i][j] = __builtin_amdgcn_mfma_f32_16x16x32_bf16(af[i], bfr[j], acc[i][j], 0, 0, 0);
        __syncthreads();
    }

    int mbase = bm*64 + wr*32;
    int nbase = bn*128 + wc*64;
    #pragma unroll
    for (int j = 0; j < 4; ++j) {
        int col = nbase + j*16 + fr;
        float bv = bias[col];
        #pragma unroll
        for (int i = 0; i < 2; ++i) {
            int r0 = mbase + i*16 + fq*4;
            #pragma unroll
            for (int r = 0; r < 4; ++r)
                out[(size_t)(r0 + r)*C_ + col] = acc[i][j][r] + bv;
        }
    }
}

// ---------------- flash attention (R11-verified): staged + in-block 2-way KV split ----------------
__device__ __forceinline__ void attn_subtile(
    const short8 (&kf)[4], const short8 (&qf)[4],
    const short8 (&vlo)[2], const short8 (&vhi)[2],
    bool diag, int l31, int hi,
    f32x16& o0, f32x16& o1, float& m_, float& l_)
{
    f32x16 a0 = {};
    __builtin_amdgcn_s_setprio(1);
    a0 = __builtin_amdgcn_mfma_f32_32x32x16_bf16(kf[0], qf[0], a0, 0, 0, 0);
    a0 = __builtin_amdgcn_mfma_f32_32x32x16_bf16(kf[1], qf[1], a0, 0, 0, 0);
    a0 = __builtin_amdgcn_mfma_f32_32x32x16_bf16(kf[2], qf[2], a0, 0, 0, 0);
    a0 = __builtin_amdgcn_mfma_f32_32x32x16_bf16(kf[3], qf[3], a0, 0, 0, 0);
    __builtin_amdgcn_s_setprio(0);

    if (diag) {
        #pragma unroll
        for (int r = 0; r < 16; ++r) {
            int kvl = (r&3) + 8*(r>>2) + 4*hi;
            if (kvl > l31) a0[r] = -1e30f;
        }
    }

    float x0 = fmaxf(a0[0], a0[1]),   x1 = fmaxf(a0[2], a0[3]);
    float x2 = fmaxf(a0[4], a0[5]),   x3 = fmaxf(a0[6], a0[7]);
    float x4 = fmaxf(a0[8], a0[9]),   x5 = fmaxf(a0[10], a0[11]);
    float x6 = fmaxf(a0[12], a0[13]), x7 = fmaxf(a0[14], a0[15]);
    float y0 = fmaxf(x0, x1), y1 = fmaxf(x2, x3), y2 = fmaxf(x4, x5), y3 = fmaxf(x6, x7);
    float pm = fmaxf(fmaxf(y0, y1), fmaxf(y2, y3));
    pm = xhalf_max(pm);

    if (!__all(pm - m_ <= 8.0f)) {
        float mn = fmaxf(m_, pm);
        float alpha = fexp2(m_ - mn);
        l_ *= alpha;
        m_ = mn;
        #pragma unroll
        for (int r = 0; r < 16; ++r) {
            int row = (r&3) + 8*(r>>2) + 4*hi;
            float ar = __shfl(alpha, row);
            o0[r] *= ar;
            o1[r] *= ar;
        }
    }

    #pragma unroll
    for (int r = 0; r < 16; ++r)
        a0[r] = fexp2(a0[r] - m_);
    float s0 = a0[0]+a0[1],  s1 = a0[2]+a0[3],  s2 = a0[4]+a0[5],   s3 = a0[6]+a0[7];
    float s4 = a0[8]+a0[9],  s5 = a0[10]+a0[11], s6 = a0[12]+a0[13], s7 = a0[14]+a0[15];
    float u0 = s0+s1, u1 = s2+s3, u2 = s4+s5, u3 = s6+s7;
    float rs = (u0+u1) + (u2+u3);
    rs = xhalf_sum(rs);
    l_ += rs;

    unsigned pk_[8];
    #pragma unroll
    for (int jj = 0; jj < 8; ++jj)
        pk_[jj] = cvtpk_bf16(a0[2*jj], a0[2*jj+1]);

    #pragma unroll
    for (int kb = 0; kb < 2; ++kb) {
        unsigned fx = pk_[4*kb+0], fz = pk_[4*kb+2];
        unsigned fy = pk_[4*kb+1], fw = pk_[4*kb+3];
        plswap(fx, fz);
        plswap(fy, fw);
        u32x4 wv;
        wv.x = fx; wv.y = fy; wv.z = fz; wv.w = fw;
        short8 pfrag = __builtin_bit_cast(short8, wv);
        __builtin_amdgcn_s_setprio(1);
        o0 = __builtin_amdgcn_mfma_f32_32x32x16_bf16(pfrag, vlo[kb], o0, 0, 0, 0);
        o1 = __builtin_amdgcn_mfma_f32_32x32x16_bf16(pfrag, vhi[kb], o1, 0, 0, 0);
        __builtin_amdgcn_s_setprio(0);
    }
}

__global__ __launch_bounds__(256, 2) void flash_attn(
    const unsigned short* __restrict__ q,
    const unsigned short* __restrict__ k,
    const unsigned short* __restrict__ vt,
    unsigned short* __restrict__ y)
{
    // staging: [buf][tensor][4096 shorts]; tensors: 0=K_lo 1=K_hi 2=V_lo 3=V_hi (64 KB)
    __shared__ __align__(16) unsigned short ST[2][4][4096];
    // merge overlay (used only after the final compute barrier):
    float* oP  = reinterpret_cast<float*>(&ST[0][0][0]);   // [4 sets][32 rows][68]
    float* mlP = oP + 4*32*68;                             // m: [set*32+l31], l: +128

    int tid = threadIdx.x, lane = tid & 63, w = tid >> 6;
    int l31 = lane & 31, hi = lane >> 5, rsw = l31 & 7;
    int role = w >> 1, pair = w & 1;
    int bid = blockIdx.x;

    // balanced complementary mapping: co-resident blocks (bid, bid+256) have S summing to 15
    int half = bid >> 8;              // 0 or 1
    int idx  = bid & 255;
    int bh   = (idx & 7)*4 + ((idx >> 3) & 3);   // 4 heads per XCD
    int sidx = idx >> 5;              // 0..7
    int S    = half ? sidx : (15 - sidx);        // heavy half first

    const unsigned short* kp = k  + (size_t)bh*T_*D_;
    const unsigned short* vp = vt + (size_t)bh*D_*T_;

    int rowbase = S*128 + pair*64;    // this wave-pair's first q row
    const unsigned short* qp = q + ((size_t)bh*T_ + rowbase) * D_;

    short8 qf0[4], qf1[4];
    #pragma unroll
    for (int dk = 0; dk < 4; ++dk) {
        qf0[dk] = *reinterpret_cast<const short8*>(qp + (size_t)l31*D_        + dk*16 + hi*8);
        qf1[dk] = *reinterpret_cast<const short8*>(qp + (size_t)(32 + l31)*D_ + dk*16 + hi*8);
    }

    f32x16 o00 = {}, o01 = {}, o10 = {}, o11 = {};
    float m0 = -1e30f, l0 = 0.f, m1 = -1e30f, l1 = 0.f;

    int lim0 = 4*S + 2*pair;          // chain0 diag sub-tile (global g)
    int lim1 = lim0 + 1;              // chain1
    int niter = S + 1;                // tiles per stream

    // stage iteration ii: low tile = ii, high tile = S+1+ii (512 chunks/tensor)
    #define STAGE(ii, bufi)                                                            \
    {                                                                                  \
        _Pragma("unroll")                                                              \
        for (int jj = 0; jj < 2; ++jj) {                                               \
            int c2 = tid + jj*256;                                                     \
            int row_ = c2 >> 3;                                                        \
            int slot_ = (c2 & 7) ^ (row_ & 7);                                         \
            int tl_ = (ii), th_ = S + 1 + (ii);                                        \
            gload16(kp + ((size_t)(tl_*64 + row_))*D_ + slot_*8, &ST[bufi][0][c2*8]);  \
            gload16(kp + ((size_t)(th_*64 + row_))*D_ + slot_*8, &ST[bufi][1][c2*8]);  \
            gload16(vp + (size_t)row_*T_ + tl_*64 + slot_*8,     &ST[bufi][2][c2*8]);  \
            gload16(vp + (size_t)row_*T_ + th_*64 + slot_*8,     &ST[bufi][3][c2*8]);  \
        }                                                                              \
    }

    STAGE(0, 0);
    __syncthreads();

    for (int i = 0; i < niter; ++i) {
        int bufi = i & 1;
        if (i + 1 < niter) STAGE(i + 1, bufi ^ 1);

        const unsigned short* Kl = &ST[bufi][role][0];
        const unsigned short* Vl = &ST[bufi][2 + role][0];
        int t = role ? (S + 1 + i) : i;

        #pragma unroll
        for (int st = 0; st < 2; ++st) {
            int g = 2*t + st;
            if (g <= lim1) {
                short8 kf[4];
                const unsigned short* kr = Kl + (st*32 + l31)*64;
                #pragma unroll
                for (int dk = 0; dk < 4; ++dk)
                    kf[dk] = *reinterpret_cast<const short8*>(kr + (((dk<<1)|hi) ^ rsw)*8);
                short8 vlo[2], vhi[2];
                const unsigned short* vr0 = Vl + l31*64;
                const unsigned short* vr1 = Vl + (32 + l31)*64;
                #pragma unroll
                for (int kb = 0; kb < 2; ++kb) {
                    int sl = (((st<<2) | (kb<<1) | hi) ^ rsw) * 8;
                    vlo[kb] = *reinterpret_cast<const short8*>(vr0 + sl);
                    vhi[kb] = *reinterpret_cast<const short8*>(vr1 + sl);
                }
                if (g <= lim0)
                    attn_subtile(kf, qf0, vlo, vhi, g == lim0, l31, hi, o00, o01, m0, l0);
                attn_subtile(kf, qf1, vlo, vhi, g == lim1, l31, hi, o10, o11, m1, l1);
            }
        }
        __syncthreads();
    }
    #undef STAGE

    // ---- merge the two KV halves (low waves store; high waves combine + write) ----
    if (!role) {
        int s0 = pair*2, s1 = pair*2 + 1;
        #pragma unroll
        for (int rr = 0; rr < 16; ++rr) {
            int crow = (rr&3) + 8*(rr>>2) + 4*hi;
            oP[(s0*32 + crow)*68 + l31]      = o00[rr];
            oP[(s0*32 + crow)*68 + 32 + l31] = o01[rr];
            oP[(s1*32 + crow)*68 + l31]      = o10[rr];
            oP[(s1*32 + crow)*68 + 32 + l31] = o11[rr];
        }
        if (!hi) {
            mlP[s0*32 + l31]       = m0;
            mlP[128 + s0*32 + l31] = l0;
            mlP[s1*32 + l31]       = m1;
            mlP[128 + s1*32 + l31] = l1;
        }
    }
    __syncthreads();
    if (role) {
        int b = bh >> 4, h = bh & 15;
        #pragma unroll
        for (int qq = 0; qq < 2; ++qq) {
            int set = pair*2 + qq;
            const f32x16& po0 = qq ? o10 : o00;
            const f32x16& po1 = qq ? o11 : o01;
            float m_ = qq ? m1 : m0;
            float l_ = qq ? l1 : l0;

            float mA = mlP[set*32 + l31];
            float lA = mlP[128 + set*32 + l31];
            float mN = fmaxf(mA, m_);
            float aA = fexp2(mA - mN);
            float aB = fexp2(m_ - mN);
            float lN = lA*aA + l_*aB;
            float inv = 1.0f / lN;
            float cA = aA * inv, cB = aB * inv;

            #pragma unroll
            for (int rr = 0; rr < 16; ++rr) {
                int crow = (rr&3) + 8*(rr>>2) + 4*hi;
                float cAr = __shfl(cA, crow);
                float cBr = __shfl(cB, crow);
                float vA0 = oP[(set*32 + crow)*68 + l31];
                float vA1 = oP[(set*32 + crow)*68 + 32 + l31];
                int trow = rowbase + qq*32 + crow;
                size_t base = ((size_t)(b*T_ + trow))*C_ + h*64;
                y[base + l31]      = f2bf(vA0*cAr + po0[rr]*cBr);
                y[base + 32 + l31] = f2bf(vA1*cAr + po1[rr]*cBr);
            }
        }
    }
}

extern "C" void kernel_launch(void* const* d_in, const int* in_sizes, int n_in,
                              void* d_out, int out_size, void* d_ws, size_t ws_size,
                              hipStream_t stream) {
    const float* x  = (const float*)d_in[0];
    const float* Wk = (const float*)d_in[1];
    const float* bk = (const float*)d_in[2];
    const float* Wq = (const float*)d_in[3];
    const float* bq = (const float*)d_in[4];
    const float* Wv = (const float*)d_in[5];
    const float* bv = (const float*)d_in[6];
    const float* Wo = (const float*)d_in[7];
    const float* bo = (const float*)d_in[8];
    float* out = (float*)d_out;

    char* ws = (char*)d_ws;
    unsigned short* xb  = (unsigned short*)(ws);                    // 8MB
    unsigned short* wkb = (unsigned short*)(ws + ((size_t)8  << 20));
    unsigned short* wqb = (unsigned short*)(ws + ((size_t)10 << 20));
    unsigned short* wvb = (unsigned short*)(ws + ((size_t)12 << 20));
    unsigned short* wob = (unsigned short*)(ws + ((size_t)14 << 20));
    unsigned short* qb  = (unsigned short*)(ws + ((size_t)16 << 20)); // [B,H,T,D]
    unsigned short* kb  = (unsigned short*)(ws + ((size_t)24 << 20)); // [B,H,T,D]
    unsigned short* vtb = (unsigned short*)(ws + ((size_t)32 << 20)); // [B,H,D,T]
    unsigned short* yb  = (unsigned short*)(ws + ((size_t)40 << 20)); // [B*T,C]

    cvt_all<<<dim3(8192), dim3(256), 0, stream>>>(
        x, Wk, Wq, Wv, Wo, xb, wkb, wqb, wvb, wob);

    gemm_qkv<<<dim3(1536), dim3(256), 0, stream>>>(xb, wkb, wqb, wvb, bk, bq, bv, kb, qb, vtb);

    flash_attn<<<dim3(512), dim3(256), 0, stream>>>(qb, kb, vtb, yb);

    gemm_out<<<dim3(512), dim3(256), 0, stream>>>(yb, wob, bo, out);
}

// Round 15
// 107.134 us; speedup vs baseline: 2.0773x; 1.1142x over previous
//
#include <hip/hip_runtime.h>
#include <hip/hip_bf16.h>
#include <stdint.h>
#include <stddef.h>

#define B_ 2
#define T_ 2048
#define C_ 1024
#define H_ 16
#define D_ 64
#define M_ (B_*T_)   // 4096

typedef __attribute__((ext_vector_type(8))) short short8;
typedef __attribute__((ext_vector_type(4))) float f32x4;
typedef __attribute__((ext_vector_type(16))) float f32x16;
typedef __attribute__((ext_vector_type(4))) unsigned int u32x4;

__device__ __forceinline__ unsigned short f2bf(float f) {
    unsigned u = __float_as_uint(f);
    unsigned r = 0x7FFFu + ((u >> 16) & 1u);
    return (unsigned short)((u + r) >> 16);
}

__device__ __forceinline__ unsigned cvtpk_bf16(float lo, float hi) {
    unsigned r;
    asm("v_cvt_pk_bf16_f32 %0, %1, %2" : "=v"(r) : "v"(lo), "v"(hi));
    return r;
}

// guaranteed single-instruction 2^x
__device__ __forceinline__ float fexp2(float x) {
    float r;
    asm("v_exp_f32 %0, %1" : "=v"(r) : "v"(x));
    return r;
}

// v_permlane32_swap_b32: a = [a_lo | b_lo], b = [a_hi | b_hi]
__device__ __forceinline__ void plswap(unsigned &a, unsigned &b) {
    asm("v_permlane32_swap_b32 %0, %1" : "+v"(a), "+v"(b));
}

__device__ __forceinline__ float xhalf_max(float v) {
    float a = v, b = v;
    asm("" : "+v"(b));
    asm("v_permlane32_swap_b32 %0, %1" : "+v"(a), "+v"(b));
    return fmaxf(a, b);
}
__device__ __forceinline__ float xhalf_sum(float v) {
    float a = v, b = v;
    asm("" : "+v"(b));
    asm("v_permlane32_swap_b32 %0, %1" : "+v"(a), "+v"(b));
    return a + b;
}

__device__ __forceinline__ void gload16(const void* g, void* l) {
    __builtin_amdgcn_global_load_lds(
        (__attribute__((address_space(1))) void*)g,
        (__attribute__((address_space(3))) void*)l,
        16, 0, 0);
}

// ---------------- fp32 -> bf16 conversion: all 5 tensors, one launch ----------------
__global__ void cvt_all(const float* __restrict__ x,  const float* __restrict__ wk,
                        const float* __restrict__ wq, const float* __restrict__ wv,
                        const float* __restrict__ wo,
                        unsigned short* __restrict__ xb,  unsigned short* __restrict__ wkb,
                        unsigned short* __restrict__ wqb, unsigned short* __restrict__ wvb,
                        unsigned short* __restrict__ wob) {
    int idx = (blockIdx.x * blockDim.x + threadIdx.x) * 4;
    const float* in; unsigned short* out; int off;
    if      (idx < (4<<20)) { in = x;  out = xb;  off = idx; }
    else if (idx < (5<<20)) { in = wk; out = wkb; off = idx - (4<<20); }
    else if (idx < (6<<20)) { in = wq; out = wqb; off = idx - (5<<20); }
    else if (idx < (7<<20)) { in = wv; out = wvb; off = idx - (6<<20); }
    else                    { in = wo; out = wob; off = idx - (7<<20); }
    float4 v = *reinterpret_cast<const float4*>(in + off);
    ushort4 o;
    o.x = f2bf(v.x); o.y = f2bf(v.y); o.z = f2bf(v.z); o.w = f2bf(v.w);
    *reinterpret_cast<ushort4*>(out + off) = o;
}

// ---------------- fused QKV projection GEMM (R9-verified: 128x128, BK=32) ----------------
// which 0 -> K [B,H,T,D], which 1 -> Q*scale [B,H,T,D], which 2 -> V^T [B,H,D,T]
__global__ __launch_bounds__(256) void gemm_qkv(
    const unsigned short* __restrict__ A,
    const unsigned short* __restrict__ W0,
    const unsigned short* __restrict__ W1,
    const unsigned short* __restrict__ W2,
    const float* __restrict__ b0,
    const float* __restrict__ b1,
    const float* __restrict__ b2,
    unsigned short* __restrict__ o0,   // k
    unsigned short* __restrict__ o1,   // q (pre-scaled by LOG2E/32)
    unsigned short* __restrict__ o2)   // vt
{
    __shared__ unsigned short As[128*32];
    __shared__ unsigned short Bs[128*32];
    int which = blockIdx.x >> 8;
    int bx = blockIdx.x & 255;
    int bm = bx >> 3, bn = bx & 7;
    const unsigned short* W = (which==0) ? W0 : ((which==1) ? W1 : W2);
    const float* bias = (which==0) ? b0 : ((which==1) ? b1 : b2);

    int tid = threadIdx.x;
    int lane = tid & 63;
    int fr = lane & 15, fq = lane >> 4;
    int wid = tid >> 6;
    int wr = wid >> 1, wc = wid & 1;

    int srow = tid >> 2;            // 0..63
    int scol = (tid & 3) << 3;      // 0,8,16,24
    const unsigned short* Ab = A + (size_t)(bm*128 + srow) * C_ + scol;
    const unsigned short* Wb = W + (size_t)(bn*128 + srow) * C_ + scol;

    f32x4 acc[4][4] = {};

    for (int kt = 0; kt < C_/32; ++kt) {
        int ko = kt*32;
        gload16(Ab + ko,            &As[tid*8]);
        gload16(Ab + 64*C_ + ko,    &As[2048 + tid*8]);
        gload16(Wb + ko,            &Bs[tid*8]);
        gload16(Wb + 64*C_ + ko,    &Bs[2048 + tid*8]);
        __syncthreads();
        short8 af[4], bfr[4];
        #pragma unroll
        for (int i = 0; i < 4; ++i) {
            af[i]  = *reinterpret_cast<const short8*>(&As[(wr*64 + i*16 + fr)*32 + fq*8]);
            bfr[i] = *reinterpret_cast<const short8*>(&Bs[(wc*64 + i*16 + fr)*32 + fq*8]);
        }
        #pragma unroll
        for (int i = 0; i < 4; ++i)
            #pragma unroll
            for (int j = 0; j < 4; ++j)
                acc[i][j] = __builtin_amdgcn_mfma_f32_16x16x32_bf16(af[i], bfr[j], acc[i][j], 0, 0, 0);
        __syncthreads();
    }

    // Q: fold 1/sqrt(C)=1/32 AND log2(e) so QK^T lands in log2 domain
    float sc = (which == 1) ? 0.045084220f : 1.0f;
    int mbase = bm*128 + wr*64;
    int nbase = bn*128 + wc*64;
    #pragma unroll
    for (int j = 0; j < 4; ++j) {
        int col = nbase + j*16 + fr;
        float bv = bias[col];
        int h = col >> 6, d = col & 63;
        #pragma unroll
        for (int i = 0; i < 4; ++i) {
            int r0 = mbase + i*16 + fq*4;
            #pragma unroll
            for (int r = 0; r < 4; ++r) {
                float v = (acc[i][j][r] + bv) * sc;
                int m = r0 + r;
                int b = m >> 11, t = m & (T_-1);
                unsigned short hv = f2bf(v);
                if (which == 2)
                    o2[((size_t)(b*H_ + h)*D_ + d)*T_ + t] = hv;
                else {
                    unsigned short* o = (which==0) ? o0 : o1;
                    o[((size_t)(b*H_ + h)*T_ + t)*D_ + d] = hv;
                }
            }
        }
    }
}

// ---------------- output projection GEMM (R14-verified: 64x128, BK=32) ----------------
__global__ __launch_bounds__(256, 6) void gemm_out(
    const unsigned short* __restrict__ A,   // y bf16 [M_][C_]
    const unsigned short* __restrict__ W,   // Wo bf16 [C_][C_]
    const float* __restrict__ bias,
    float* __restrict__ out)
{
    __shared__ unsigned short As[64*32];
    __shared__ unsigned short Bs[128*32];
    int bx = blockIdx.x;
    int bm = bx >> 3, bn = bx & 7;

    int tid = threadIdx.x;
    int lane = tid & 63;
    int fr = lane & 15, fq = lane >> 4;
    int wid = tid >> 6;
    int wr = wid >> 1, wc = wid & 1;

    int arow = tid >> 2;
    int acol = (tid & 3) << 3;
    const unsigned short* Ab = A + (size_t)(bm*64 + arow) * C_ + acol;
    const unsigned short* Wb = W + (size_t)(bn*128 + arow) * C_ + acol;

    f32x4 acc[2][4] = {};

    for (int kt = 0; kt < C_/32; ++kt) {
        int ko = kt*32;
        gload16(Ab + ko,            &As[tid*8]);
        gload16(Wb + ko,            &Bs[tid*8]);
        gload16(Wb + 64*C_ + ko,    &Bs[2048 + tid*8]);
        __syncthreads();
        short8 af[2], bfr[4];
        #pragma unroll
        for (int i = 0; i < 2; ++i)
            af[i]  = *reinterpret_cast<const short8*>(&As[(wr*32 + i*16 + fr)*32 + fq*8]);
        #pragma unroll
        for (int j = 0; j < 4; ++j)
            bfr[j] = *reinterpret_cast<const short8*>(&Bs[(wc*64 + j*16 + fr)*32 + fq*8]);
        #pragma unroll
        for (int i = 0; i < 2; ++i)
            #pragma unroll
            for (int j = 0; j < 4; ++j)
                acc[i][j] = __builtin_amdgcn_mfma_f32_16x16x32_bf16(af[i], bfr[j], acc[i][j], 0, 0, 0);
        __syncthreads();
    }

    int mbase = bm*64 + wr*32;
    int nbase = bn*128 + wc*64;
    #pragma unroll
    for (int j = 0; j < 4; ++j) {
        int col = nbase + j*16 + fr;
        float bv = bias[col];
        #pragma unroll
        for (int i = 0; i < 2; ++i) {
            int r0 = mbase + i*16 + fq*4;
            #pragma unroll
            for (int r = 0; r < 4; ++r)
                out[(size_t)(r0 + r)*C_ + col] = acc[i][j][r] + bv;
        }
    }
}

// ---------------- flash attention (R11-verified): staged + in-block 2-way KV split ----------------
__device__ __forceinline__ void attn_subtile(
    const short8 (&kf)[4], const short8 (&qf)[4],
    const short8 (&vlo)[2], const short8 (&vhi)[2],
    bool diag, int l31, int hi,
    f32x16& o0, f32x16& o1, float& m_, float& l_)
{
    f32x16 a0 = {};
    __builtin_amdgcn_s_setprio(1);
    a0 = __builtin_amdgcn_mfma_f32_32x32x16_bf16(kf[0], qf[0], a0, 0, 0, 0);
    a0 = __builtin_amdgcn_mfma_f32_32x32x16_bf16(kf[1], qf[1], a0, 0, 0, 0);
    a0 = __builtin_amdgcn_mfma_f32_32x32x16_bf16(kf[2], qf[2], a0, 0, 0, 0);
    a0 = __builtin_amdgcn_mfma_f32_32x32x16_bf16(kf[3], qf[3], a0, 0, 0, 0);
    __builtin_amdgcn_s_setprio(0);

    if (diag) {
        #pragma unroll
        for (int r = 0; r < 16; ++r) {
            int kvl = (r&3) + 8*(r>>2) + 4*hi;
            if (kvl > l31) a0[r] = -1e30f;
        }
    }

    float x0 = fmaxf(a0[0], a0[1]),   x1 = fmaxf(a0[2], a0[3]);
    float x2 = fmaxf(a0[4], a0[5]),   x3 = fmaxf(a0[6], a0[7]);
    float x4 = fmaxf(a0[8], a0[9]),   x5 = fmaxf(a0[10], a0[11]);
    float x6 = fmaxf(a0[12], a0[13]), x7 = fmaxf(a0[14], a0[15]);
    float y0 = fmaxf(x0, x1), y1 = fmaxf(x2, x3), y2 = fmaxf(x4, x5), y3 = fmaxf(x6, x7);
    float pm = fmaxf(fmaxf(y0, y1), fmaxf(y2, y3));
    pm = xhalf_max(pm);

    if (!__all(pm - m_ <= 8.0f)) {
        float mn = fmaxf(m_, pm);
        float alpha = fexp2(m_ - mn);
        l_ *= alpha;
        m_ = mn;
        #pragma unroll
        for (int r = 0; r < 16; ++r) {
            int row = (r&3) + 8*(r>>2) + 4*hi;
            float ar = __shfl(alpha, row);
            o0[r] *= ar;
            o1[r] *= ar;
        }
    }

    #pragma unroll
    for (int r = 0; r < 16; ++r)
        a0[r] = fexp2(a0[r] - m_);
    float s0 = a0[0]+a0[1],  s1 = a0[2]+a0[3],  s2 = a0[4]+a0[5],   s3 = a0[6]+a0[7];
    float s4 = a0[8]+a0[9],  s5 = a0[10]+a0[11], s6 = a0[12]+a0[13], s7 = a0[14]+a0[15];
    float u0 = s0+s1, u1 = s2+s3, u2 = s4+s5, u3 = s6+s7;
    float rs = (u0+u1) + (u2+u3);
    rs = xhalf_sum(rs);
    l_ += rs;

    unsigned pk_[8];
    #pragma unroll
    for (int jj = 0; jj < 8; ++jj)
        pk_[jj] = cvtpk_bf16(a0[2*jj], a0[2*jj+1]);

    #pragma unroll
    for (int kb = 0; kb < 2; ++kb) {
        unsigned fx = pk_[4*kb+0], fz = pk_[4*kb+2];
        unsigned fy = pk_[4*kb+1], fw = pk_[4*kb+3];
        plswap(fx, fz);
        plswap(fy, fw);
        u32x4 wv;
        wv.x = fx; wv.y = fy; wv.z = fz; wv.w = fw;
        short8 pfrag = __builtin_bit_cast(short8, wv);
        __builtin_amdgcn_s_setprio(1);
        o0 = __builtin_amdgcn_mfma_f32_32x32x16_bf16(pfrag, vlo[kb], o0, 0, 0, 0);
        o1 = __builtin_amdgcn_mfma_f32_32x32x16_bf16(pfrag, vhi[kb], o1, 0, 0, 0);
        __builtin_amdgcn_s_setprio(0);
    }
}

__global__ __launch_bounds__(256, 2) void flash_attn(
    const unsigned short* __restrict__ q,
    const unsigned short* __restrict__ k,
    const unsigned short* __restrict__ vt,
    unsigned short* __restrict__ y)
{
    // staging: [buf][tensor][4096 shorts]; tensors: 0=K_lo 1=K_hi 2=V_lo 3=V_hi (64 KB)
    __shared__ __align__(16) unsigned short ST[2][4][4096];
    // merge overlay (used only after the final compute barrier):
    float* oP  = reinterpret_cast<float*>(&ST[0][0][0]);   // [4 sets][32 rows][68]
    float* mlP = oP + 4*32*68;                             // m: [set*32+l31], l: +128

    int tid = threadIdx.x, lane = tid & 63, w = tid >> 6;
    int l31 = lane & 31, hi = lane >> 5, rsw = l31 & 7;
    int role = w >> 1, pair = w & 1;
    int bid = blockIdx.x;

    // balanced complementary mapping: co-resident blocks (bid, bid+256) have S summing to 15
    int half = bid >> 8;              // 0 or 1
    int idx  = bid & 255;
    int bh   = (idx & 7)*4 + ((idx >> 3) & 3);   // 4 heads per XCD
    int sidx = idx >> 5;              // 0..7
    int S    = half ? sidx : (15 - sidx);        // heavy half first

    const unsigned short* kp = k  + (size_t)bh*T_*D_;
    const unsigned short* vp = vt + (size_t)bh*D_*T_;

    int rowbase = S*128 + pair*64;    // this wave-pair's first q row
    const unsigned short* qp = q + ((size_t)bh*T_ + rowbase) * D_;

    short8 qf0[4], qf1[4];
    #pragma unroll
    for (int dk = 0; dk < 4; ++dk) {
        qf0[dk] = *reinterpret_cast<const short8*>(qp + (size_t)l31*D_        + dk*16 + hi*8);
        qf1[dk] = *reinterpret_cast<const short8*>(qp + (size_t)(32 + l31)*D_ + dk*16 + hi*8);
    }

    f32x16 o00 = {}, o01 = {}, o10 = {}, o11 = {};
    float m0 = -1e30f, l0 = 0.f, m1 = -1e30f, l1 = 0.f;

    int lim0 = 4*S + 2*pair;          // chain0 diag sub-tile (global g)
    int lim1 = lim0 + 1;              // chain1
    int niter = S + 1;                // tiles per stream

    // stage iteration ii: low tile = ii, high tile = S+1+ii (512 chunks/tensor)
    #define STAGE(ii, bufi)                                                            \
    {                                                                                  \
        _Pragma("unroll")                                                              \
        for (int jj = 0; jj < 2; ++jj) {                                               \
            int c2 = tid + jj*256;                                                     \
            int row_ = c2 >> 3;                                                        \
            int slot_ = (c2 & 7) ^ (row_ & 7);                                         \
            int tl_ = (ii), th_ = S + 1 + (ii);                                        \
            gload16(kp + ((size_t)(tl_*64 + row_))*D_ + slot_*8, &ST[bufi][0][c2*8]);  \
            gload16(kp + ((size_t)(th_*64 + row_))*D_ + slot_*8, &ST[bufi][1][c2*8]);  \
            gload16(vp + (size_t)row_*T_ + tl_*64 + slot_*8,     &ST[bufi][2][c2*8]);  \
            gload16(vp + (size_t)row_*T_ + th_*64 + slot_*8,     &ST[bufi][3][c2*8]);  \
        }                                                                              \
    }

    STAGE(0, 0);
    __syncthreads();

    for (int i = 0; i < niter; ++i) {
        int bufi = i & 1;
        if (i + 1 < niter) STAGE(i + 1, bufi ^ 1);

        const unsigned short* Kl = &ST[bufi][role][0];
        const unsigned short* Vl = &ST[bufi][2 + role][0];
        int t = role ? (S + 1 + i) : i;

        #pragma unroll
        for (int st = 0; st < 2; ++st) {
            int g = 2*t + st;
            if (g <= lim1) {
                short8 kf[4];
                const unsigned short* kr = Kl + (st*32 + l31)*64;
                #pragma unroll
                for (int dk = 0; dk < 4; ++dk)
                    kf[dk] = *reinterpret_cast<const short8*>(kr + (((dk<<1)|hi) ^ rsw)*8);
                short8 vlo[2], vhi[2];
                const unsigned short* vr0 = Vl + l31*64;
                const unsigned short* vr1 = Vl + (32 + l31)*64;
                #pragma unroll
                for (int kb = 0; kb < 2; ++kb) {
                    int sl = (((st<<2) | (kb<<1) | hi) ^ rsw) * 8;
                    vlo[kb] = *reinterpret_cast<const short8*>(vr0 + sl);
                    vhi[kb] = *reinterpret_cast<const short8*>(vr1 + sl);
                }
                if (g <= lim0)
                    attn_subtile(kf, qf0, vlo, vhi, g == lim0, l31, hi, o00, o01, m0, l0);
                attn_subtile(kf, qf1, vlo, vhi, g == lim1, l31, hi, o10, o11, m1, l1);
            }
        }
        __syncthreads();
    }
    #undef STAGE

    // ---- merge the two KV halves (low waves store; high waves combine + write) ----
    if (!role) {
        int s0 = pair*2, s1 = pair*2 + 1;
        #pragma unroll
        for (int rr = 0; rr < 16; ++rr) {
            int crow = (rr&3) + 8*(rr>>2) + 4*hi;
            oP[(s0*32 + crow)*68 + l31]      = o00[rr];
            oP[(s0*32 + crow)*68 + 32 + l31] = o01[rr];
            oP[(s1*32 + crow)*68 + l31]      = o10[rr];
            oP[(s1*32 + crow)*68 + 32 + l31] = o11[rr];
        }
        if (!hi) {
            mlP[s0*32 + l31]       = m0;
            mlP[128 + s0*32 + l31] = l0;
            mlP[s1*32 + l31]       = m1;
            mlP[128 + s1*32 + l31] = l1;
        }
    }
    __syncthreads();
    if (role) {
        int b = bh >> 4, h = bh & 15;
        #pragma unroll
        for (int qq = 0; qq < 2; ++qq) {
            int set = pair*2 + qq;
            const f32x16& po0 = qq ? o10 : o00;
            const f32x16& po1 = qq ? o11 : o01;
            float m_ = qq ? m1 : m0;
            float l_ = qq ? l1 : l0;

            float mA = mlP[set*32 + l31];
            float lA = mlP[128 + set*32 + l31];
            float mN = fmaxf(mA, m_);
            float aA = fexp2(mA - mN);
            float aB = fexp2(m_ - mN);
            float lN = lA*aA + l_*aB;
            float inv = 1.0f / lN;
            float cA = aA * inv, cB = aB * inv;

            #pragma unroll
            for (int rr = 0; rr < 16; ++rr) {
                int crow = (rr&3) + 8*(rr>>2) + 4*hi;
                float cAr = __shfl(cA, crow);
                float cBr = __shfl(cB, crow);
                float vA0 = oP[(set*32 + crow)*68 + l31];
                float vA1 = oP[(set*32 + crow)*68 + 32 + l31];
                int trow = rowbase + qq*32 + crow;
                size_t base = ((size_t)(b*T_ + trow))*C_ + h*64;
                y[base + l31]      = f2bf(vA0*cAr + po0[rr]*cBr);
                y[base + 32 + l31] = f2bf(vA1*cAr + po1[rr]*cBr);
            }
        }
    }
}

extern "C" void kernel_launch(void* const* d_in, const int* in_sizes, int n_in,
                              void* d_out, int out_size, void* d_ws, size_t ws_size,
                              hipStream_t stream) {
    const float* x  = (const float*)d_in[0];
    const float* Wk = (const float*)d_in[1];
    const float* bk = (const float*)d_in[2];
    const float* Wq = (const float*)d_in[3];
    const float* bq = (const float*)d_in[4];
    const float* Wv = (const float*)d_in[5];
    const float* bv = (const float*)d_in[6];
    const float* Wo = (const float*)d_in[7];
    const float* bo = (const float*)d_in[8];
    float* out = (float*)d_out;

    char* ws = (char*)d_ws;
    unsigned short* xb  = (unsigned short*)(ws);                    // 8MB
    unsigned short* wkb = (unsigned short*)(ws + ((size_t)8  << 20));
    unsigned short* wqb = (unsigned short*)(ws + ((size_t)10 << 20));
    unsigned short* wvb = (unsigned short*)(ws + ((size_t)12 << 20));
    unsigned short* wob = (unsigned short*)(ws + ((size_t)14 << 20));
    unsigned short* qb  = (unsigned short*)(ws + ((size_t)16 << 20)); // [B,H,T,D]
    unsigned short* kb  = (unsigned short*)(ws + ((size_t)24 << 20)); // [B,H,T,D]
    unsigned short* vtb = (unsigned short*)(ws + ((size_t)32 << 20)); // [B,H,D,T]
    unsigned short* yb  = (unsigned short*)(ws + ((size_t)40 << 20)); // [B*T,C]

    cvt_all<<<dim3(8192), dim3(256), 0, stream>>>(
        x, Wk, Wq, Wv, Wo, xb, wkb, wqb, wvb, wob);

    gemm_qkv<<<dim3(768), dim3(256), 0, stream>>>(xb, wkb, wqb, wvb, bk, bq, bv, kb, qb, vtb);

    flash_attn<<<dim3(512), dim3(256), 0, stream>>>(qb, kb, vtb, yb);

    gemm_out<<<dim3(512), dim3(256), 0, stream>>>(yb, wob, bo, out);
}

// Round 16
// 102.643 us; speedup vs baseline: 2.1682x; 1.0438x over previous
//
#include <hip/hip_runtime.h>
#include <hip/hip_bf16.h>
#include <stdint.h>
#include <stddef.h>

#define B_ 2
#define T_ 2048
#define C_ 1024
#define H_ 16
#define D_ 64
#define M_ (B_*T_)   // 4096

typedef __attribute__((ext_vector_type(8))) short short8;
typedef __attribute__((ext_vector_type(4))) float f32x4;
typedef __attribute__((ext_vector_type(16))) float f32x16;
typedef __attribute__((ext_vector_type(4))) unsigned int u32x4;

__device__ __forceinline__ unsigned short f2bf(float f) {
    unsigned u = __float_as_uint(f);
    unsigned r = 0x7FFFu + ((u >> 16) & 1u);
    return (unsigned short)((u + r) >> 16);
}

__device__ __forceinline__ unsigned cvtpk_bf16(float lo, float hi) {
    unsigned r;
    asm("v_cvt_pk_bf16_f32 %0, %1, %2" : "=v"(r) : "v"(lo), "v"(hi));
    return r;
}

// guaranteed single-instruction 2^x
__device__ __forceinline__ float fexp2(float x) {
    float r;
    asm("v_exp_f32 %0, %1" : "=v"(r) : "v"(x));
    return r;
}

// v_permlane32_swap_b32: a = [a_lo | b_lo], b = [a_hi | b_hi]
__device__ __forceinline__ void plswap(unsigned &a, unsigned &b) {
    asm("v_permlane32_swap_b32 %0, %1" : "+v"(a), "+v"(b));
}

__device__ __forceinline__ float xhalf_max(float v) {
    float a = v, b = v;
    asm("" : "+v"(b));
    asm("v_permlane32_swap_b32 %0, %1" : "+v"(a), "+v"(b));
    return fmaxf(a, b);
}
__device__ __forceinline__ float xhalf_sum(float v) {
    float a = v, b = v;
    asm("" : "+v"(b));
    asm("v_permlane32_swap_b32 %0, %1" : "+v"(a), "+v"(b));
    return a + b;
}

__device__ __forceinline__ void gload16(const void* g, void* l) {
    __builtin_amdgcn_global_load_lds(
        (__attribute__((address_space(1))) void*)g,
        (__attribute__((address_space(3))) void*)l,
        16, 0, 0);
}

// ---------------- fp32 -> bf16 conversion: all 5 tensors, one launch ----------------
__global__ void cvt_all(const float* __restrict__ x,  const float* __restrict__ wk,
                        const float* __restrict__ wq, const float* __restrict__ wv,
                        const float* __restrict__ wo,
                        unsigned short* __restrict__ xb,  unsigned short* __restrict__ wkb,
                        unsigned short* __restrict__ wqb, unsigned short* __restrict__ wvb,
                        unsigned short* __restrict__ wob) {
    int idx = (blockIdx.x * blockDim.x + threadIdx.x) * 4;
    const float* in; unsigned short* out; int off;
    if      (idx < (4<<20)) { in = x;  out = xb;  off = idx; }
    else if (idx < (5<<20)) { in = wk; out = wkb; off = idx - (4<<20); }
    else if (idx < (6<<20)) { in = wq; out = wqb; off = idx - (5<<20); }
    else if (idx < (7<<20)) { in = wv; out = wvb; off = idx - (6<<20); }
    else                    { in = wo; out = wob; off = idx - (7<<20); }
    float4 v = *reinterpret_cast<const float4*>(in + off);
    ushort4 o;
    o.x = f2bf(v.x); o.y = f2bf(v.y); o.z = f2bf(v.z); o.w = f2bf(v.w);
    *reinterpret_cast<ushort4*>(out + off) = o;
}

// ---------------- fused QKV projection GEMM (R9-verified: 128x128, BK=32) ----------------
// which 0 -> K [B,H,T,D], which 1 -> Q*scale [B,H,T,D], which 2 -> V^T [B,H,D,T]
__global__ __launch_bounds__(256) void gemm_qkv(
    const unsigned short* __restrict__ A,
    const unsigned short* __restrict__ W0,
    const unsigned short* __restrict__ W1,
    const unsigned short* __restrict__ W2,
    const float* __restrict__ b0,
    const float* __restrict__ b1,
    const float* __restrict__ b2,
    unsigned short* __restrict__ o0,   // k
    unsigned short* __restrict__ o1,   // q (pre-scaled by LOG2E/32)
    unsigned short* __restrict__ o2)   // vt
{
    __shared__ unsigned short As[128*32];
    __shared__ unsigned short Bs[128*32];
    int which = blockIdx.x >> 8;
    int bx = blockIdx.x & 255;
    int bm = bx >> 3, bn = bx & 7;
    const unsigned short* W = (which==0) ? W0 : ((which==1) ? W1 : W2);
    const float* bias = (which==0) ? b0 : ((which==1) ? b1 : b2);

    int tid = threadIdx.x;
    int lane = tid & 63;
    int fr = lane & 15, fq = lane >> 4;
    int wid = tid >> 6;
    int wr = wid >> 1, wc = wid & 1;

    int srow = tid >> 2;            // 0..63
    int scol = (tid & 3) << 3;      // 0,8,16,24
    const unsigned short* Ab = A + (size_t)(bm*128 + srow) * C_ + scol;
    const unsigned short* Wb = W + (size_t)(bn*128 + srow) * C_ + scol;

    f32x4 acc[4][4] = {};

    for (int kt = 0; kt < C_/32; ++kt) {
        int ko = kt*32;
        gload16(Ab + ko,            &As[tid*8]);
        gload16(Ab + 64*C_ + ko,    &As[2048 + tid*8]);
        gload16(Wb + ko,            &Bs[tid*8]);
        gload16(Wb + 64*C_ + ko,    &Bs[2048 + tid*8]);
        __syncthreads();
        short8 af[4], bfr[4];
        #pragma unroll
        for (int i = 0; i < 4; ++i) {
            af[i]  = *reinterpret_cast<const short8*>(&As[(wr*64 + i*16 + fr)*32 + fq*8]);
            bfr[i] = *reinterpret_cast<const short8*>(&Bs[(wc*64 + i*16 + fr)*32 + fq*8]);
        }
        #pragma unroll
        for (int i = 0; i < 4; ++i)
            #pragma unroll
            for (int j = 0; j < 4; ++j)
                acc[i][j] = __builtin_amdgcn_mfma_f32_16x16x32_bf16(af[i], bfr[j], acc[i][j], 0, 0, 0);
        __syncthreads();
    }

    // Q: fold 1/sqrt(C)=1/32 AND log2(e) so QK^T lands in log2 domain
    float sc = (which == 1) ? 0.045084220f : 1.0f;
    int mbase = bm*128 + wr*64;
    int nbase = bn*128 + wc*64;
    #pragma unroll
    for (int j = 0; j < 4; ++j) {
        int col = nbase + j*16 + fr;
        float bv = bias[col];
        int h = col >> 6, d = col & 63;
        #pragma unroll
        for (int i = 0; i < 4; ++i) {
            int r0 = mbase + i*16 + fq*4;
            #pragma unroll
            for (int r = 0; r < 4; ++r) {
                float v = (acc[i][j][r] + bv) * sc;
                int m = r0 + r;
                int b = m >> 11, t = m & (T_-1);
                unsigned short hv = f2bf(v);
                if (which == 2)
                    o2[((size_t)(b*H_ + h)*D_ + d)*T_ + t] = hv;
                else {
                    unsigned short* o = (which==0) ? o0 : o1;
                    o[((size_t)(b*H_ + h)*T_ + t)*D_ + d] = hv;
                }
            }
        }
    }
}

// ---------------- output projection GEMM (R14-verified: 64x128, BK=32) ----------------
__global__ __launch_bounds__(256, 6) void gemm_out(
    const unsigned short* __restrict__ A,   // y bf16 [M_][C_]
    const unsigned short* __restrict__ W,   // Wo bf16 [C_][C_]
    const float* __restrict__ bias,
    float* __restrict__ out)
{
    __shared__ unsigned short As[64*32];
    __shared__ unsigned short Bs[128*32];
    int bx = blockIdx.x;
    int bm = bx >> 3, bn = bx & 7;

    int tid = threadIdx.x;
    int lane = tid & 63;
    int fr = lane & 15, fq = lane >> 4;
    int wid = tid >> 6;
    int wr = wid >> 1, wc = wid & 1;

    int arow = tid >> 2;
    int acol = (tid & 3) << 3;
    const unsigned short* Ab = A + (size_t)(bm*64 + arow) * C_ + acol;
    const unsigned short* Wb = W + (size_t)(bn*128 + arow) * C_ + acol;

    f32x4 acc[2][4] = {};

    for (int kt = 0; kt < C_/32; ++kt) {
        int ko = kt*32;
        gload16(Ab + ko,            &As[tid*8]);
        gload16(Wb + ko,            &Bs[tid*8]);
        gload16(Wb + 64*C_ + ko,    &Bs[2048 + tid*8]);
        __syncthreads();
        short8 af[2], bfr[4];
        #pragma unroll
        for (int i = 0; i < 2; ++i)
            af[i]  = *reinterpret_cast<const short8*>(&As[(wr*32 + i*16 + fr)*32 + fq*8]);
        #pragma unroll
        for (int j = 0; j < 4; ++j)
            bfr[j] = *reinterpret_cast<const short8*>(&Bs[(wc*64 + j*16 + fr)*32 + fq*8]);
        #pragma unroll
        for (int i = 0; i < 2; ++i)
            #pragma unroll
            for (int j = 0; j < 4; ++j)
                acc[i][j] = __builtin_amdgcn_mfma_f32_16x16x32_bf16(af[i], bfr[j], acc[i][j], 0, 0, 0);
        __syncthreads();
    }

    int mbase = bm*64 + wr*32;
    int nbase = bn*128 + wc*64;
    #pragma unroll
    for (int j = 0; j < 4; ++j) {
        int col = nbase + j*16 + fr;
        float bv = bias[col];
        #pragma unroll
        for (int i = 0; i < 2; ++i) {
            int r0 = mbase + i*16 + fq*4;
            #pragma unroll
            for (int r = 0; r < 4; ++r)
                out[(size_t)(r0 + r)*C_ + col] = acc[i][j][r] + bv;
        }
    }
}

// ---------------- flash attention: 1 chain/wave, KVBLK=32, 4 blocks/CU ----------------
// Block = 4 waves over 64 q-rows: wave w -> chain p=w&1 (rows p*32..p*32+31),
// split s=w>>1 (kv stream). Streams: s=0 tiles [0,j+1), s=1 tiles [j+1,2j+2).
// Subtile math R11-verified; V 4-slot swizzle R13-correctness-verified.
__device__ __forceinline__ void attn_subtile(
    const short8 (&kf)[4], const short8 (&qf)[4],
    const short8 (&vlo)[2], const short8 (&vhi)[2],
    bool diag, int l31, int hi,
    f32x16& o0, f32x16& o1, float& m_, float& l_)
{
    f32x16 a0 = {};
    __builtin_amdgcn_s_setprio(1);
    a0 = __builtin_amdgcn_mfma_f32_32x32x16_bf16(kf[0], qf[0], a0, 0, 0, 0);
    a0 = __builtin_amdgcn_mfma_f32_32x32x16_bf16(kf[1], qf[1], a0, 0, 0, 0);
    a0 = __builtin_amdgcn_mfma_f32_32x32x16_bf16(kf[2], qf[2], a0, 0, 0, 0);
    a0 = __builtin_amdgcn_mfma_f32_32x32x16_bf16(kf[3], qf[3], a0, 0, 0, 0);
    __builtin_amdgcn_s_setprio(0);

    if (diag) {
        #pragma unroll
        for (int r = 0; r < 16; ++r) {
            int kvl = (r&3) + 8*(r>>2) + 4*hi;
            if (kvl > l31) a0[r] = -1e30f;
        }
    }

    float x0 = fmaxf(a0[0], a0[1]),   x1 = fmaxf(a0[2], a0[3]);
    float x2 = fmaxf(a0[4], a0[5]),   x3 = fmaxf(a0[6], a0[7]);
    float x4 = fmaxf(a0[8], a0[9]),   x5 = fmaxf(a0[10], a0[11]);
    float x6 = fmaxf(a0[12], a0[13]), x7 = fmaxf(a0[14], a0[15]);
    float y0 = fmaxf(x0, x1), y1 = fmaxf(x2, x3), y2 = fmaxf(x4, x5), y3 = fmaxf(x6, x7);
    float pm = fmaxf(fmaxf(y0, y1), fmaxf(y2, y3));
    pm = xhalf_max(pm);

    if (!__all(pm - m_ <= 8.0f)) {
        float mn = fmaxf(m_, pm);
        float alpha = fexp2(m_ - mn);
        l_ *= alpha;
        m_ = mn;
        #pragma unroll
        for (int r = 0; r < 16; ++r) {
            int row = (r&3) + 8*(r>>2) + 4*hi;
            float ar = __shfl(alpha, row);
            o0[r] *= ar;
            o1[r] *= ar;
        }
    }

    #pragma unroll
    for (int r = 0; r < 16; ++r)
        a0[r] = fexp2(a0[r] - m_);
    float s0 = a0[0]+a0[1],  s1 = a0[2]+a0[3],  s2 = a0[4]+a0[5],   s3 = a0[6]+a0[7];
    float s4 = a0[8]+a0[9],  s5 = a0[10]+a0[11], s6 = a0[12]+a0[13], s7 = a0[14]+a0[15];
    float u0 = s0+s1, u1 = s2+s3, u2 = s4+s5, u3 = s6+s7;
    float rs = (u0+u1) + (u2+u3);
    rs = xhalf_sum(rs);
    l_ += rs;

    unsigned pk_[8];
    #pragma unroll
    for (int jj = 0; jj < 8; ++jj)
        pk_[jj] = cvtpk_bf16(a0[2*jj], a0[2*jj+1]);

    #pragma unroll
    for (int kb = 0; kb < 2; ++kb) {
        unsigned fx = pk_[4*kb+0], fz = pk_[4*kb+2];
        unsigned fy = pk_[4*kb+1], fw = pk_[4*kb+3];
        plswap(fx, fz);
        plswap(fy, fw);
        u32x4 wv;
        wv.x = fx; wv.y = fy; wv.z = fz; wv.w = fw;
        short8 pfrag = __builtin_bit_cast(short8, wv);
        __builtin_amdgcn_s_setprio(1);
        o0 = __builtin_amdgcn_mfma_f32_32x32x16_bf16(pfrag, vlo[kb], o0, 0, 0, 0);
        o1 = __builtin_amdgcn_mfma_f32_32x32x16_bf16(pfrag, vhi[kb], o1, 0, 0, 0);
        __builtin_amdgcn_s_setprio(0);
    }
}

__global__ __launch_bounds__(256, 4) void flash_attn(
    const unsigned short* __restrict__ q,
    const unsigned short* __restrict__ k,
    const unsigned short* __restrict__ vt,
    unsigned short* __restrict__ y)
{
    // 35840 B LDS: staging ST[2][4][2048 shorts] (32 KB) aliased with merge overlay
    __shared__ __align__(16) char LDSRAW[35840];
    unsigned short (*ST)[4][2048] = reinterpret_cast<unsigned short(*)[4][2048]>(LDSRAW);
    float* oP = reinterpret_cast<float*>(LDSRAW);   // [4 sets][32 rows][68] = 34816 B
    float* mP = oP + 4*32*68;                       // [4][32]
    float* lP = mP + 128;                           // [4][32]

    int tid = threadIdx.x, lane = tid & 63, w = tid >> 6;
    int l31 = lane & 31, hi = lane >> 5, rsw = l31 & 7;
    int p = w & 1, s = w >> 1;        // chain, kv-split
    int bid = blockIdx.x;

    // complementary pairing: co-resident halves have j summing to 31
    int half = bid >> 9;
    int idx  = bid & 511;
    int bh   = (idx & 7)*4 + ((idx >> 3) & 3);   // 4 heads per XCD
    int jidx = idx >> 5;              // 0..15
    int j    = half ? jidx : (31 - jidx);        // 64-row group, heavy first

    const unsigned short* kp = k  + (size_t)bh*T_*D_;
    const unsigned short* vp = vt + (size_t)bh*D_*T_;
    int b = bh >> 4, h = bh & 15;

    int rowbase = j*64 + p*32;        // this wave's chain rows
    const unsigned short* qp = q + ((size_t)bh*T_ + rowbase) * D_;

    short8 qf[4];
    #pragma unroll
    for (int dk = 0; dk < 4; ++dk)
        qf[dk] = *reinterpret_cast<const short8*>(qp + (size_t)l31*D_ + dk*16 + hi*8);

    f32x16 o0 = {}, o1 = {};
    float m_ = -1e30f, l_ = 0.f;

    int lim = 2*j + p;                // diag 32-subtile index for this chain
    int niter = j + 1;                // tiles per stream
    int gbase = s ? (j + 1) : 0;

    // stage iteration ii: tiles tl = ii (stream0), th = j+1+ii (stream1)
    #define STAGE(ii, bufi)                                                           \
    {                                                                                 \
        int c2 = tid;                                                                 \
        int krow = c2 >> 3;                                                           \
        int kslot = (c2 & 7) ^ (krow & 7);                                            \
        int vrow = c2 >> 2;                                                           \
        int vslot = (c2 & 3) ^ (vrow & 3);                                            \
        int tl_ = (ii), th_ = j + 1 + (ii);                                           \
        gload16(kp + ((size_t)(tl_*32 + krow))*D_ + kslot*8, &ST[bufi][0][c2*8]);     \
        gload16(kp + ((size_t)(th_*32 + krow))*D_ + kslot*8, &ST[bufi][1][c2*8]);     \
        gload16(vp + (size_t)vrow*T_ + tl_*32 + vslot*8,     &ST[bufi][2][c2*8]);     \
        gload16(vp + (size_t)vrow*T_ + th_*32 + vslot*8,     &ST[bufi][3][c2*8]);     \
    }

    STAGE(0, 0);
    __syncthreads();

    for (int i = 0; i < niter; ++i) {
        int bufi = i & 1;
        if (i + 1 < niter) STAGE(i + 1, bufi ^ 1);

        int g = gbase + i;
        if (g <= lim) {
            const unsigned short* Kl = &ST[bufi][s][0];
            const unsigned short* Vl = &ST[bufi][2 + s][0];
            short8 kf[4];
            #pragma unroll
            for (int dk = 0; dk < 4; ++dk)
                kf[dk] = *reinterpret_cast<const short8*>(
                    Kl + l31*64 + ((((dk<<1)|hi)) ^ rsw)*8);
            short8 vlo[2], vhi[2];
            #pragma unroll
            for (int kb = 0; kb < 2; ++kb) {
                int sl = ((((kb<<1)|hi)) ^ (l31 & 3)) * 8;
                vlo[kb] = *reinterpret_cast<const short8*>(Vl + l31*32 + sl);
                vhi[kb] = *reinterpret_cast<const short8*>(Vl + (32 + l31)*32 + sl);
            }
            attn_subtile(kf, qf, vlo, vhi, g == lim, l31, hi, o0, o1, m_, l_);
        }
        __syncthreads();
    }
    #undef STAGE

    // ---- merge the two KV splits per chain (sets: chain p from waves s=0 -> set p, s=1 -> set 2+p) ----
    {
        int set = (s << 1) | p;       // = w
        #pragma unroll
        for (int rr = 0; rr < 16; ++rr) {
            int crow = (rr&3) + 8*(rr>>2) + 4*hi;
            oP[(set*32 + crow)*68 + l31]      = o0[rr];
            oP[(set*32 + crow)*68 + 32 + l31] = o1[rr];
        }
        if (!hi) { mP[set*32 + l31] = m_; lP[set*32 + l31] = l_; }
    }
    __syncthreads();
    {
        int qr = tid >> 3;            // 0..31
        int dc = tid & 7;             // 0..7
        #pragma unroll
        for (int ch = 0; ch < 2; ++ch) {
            int sA = ch, sB = 2 + ch;
            float mA = mP[sA*32 + qr], mB = mP[sB*32 + qr];
            float lA = lP[sA*32 + qr], lB = lP[sB*32 + qr];
            float mN = fmaxf(mA, mB);
            float aA = fexp2(mA - mN);
            float aB = fexp2(mB - mN);
            float lN = lA*aA + lB*aB;
            float inv = 1.0f / lN;
            float cA = aA * inv, cB = aB * inv;

            unsigned short yv[8];
            #pragma unroll
            for (int e = 0; e < 8; ++e) {
                float acc = cA * oP[(sA*32 + qr)*68 + dc*8 + e]
                          + cB * oP[(sB*32 + qr)*68 + dc*8 + e];
                yv[e] = f2bf(acc);
            }
            int trow = j*64 + ch*32 + qr;
            size_t base = ((size_t)(b*T_ + trow))*C_ + h*64 + dc*8;
            *reinterpret_cast<short8*>(y + base) = *reinterpret_cast<short8*>(yv);
        }
    }
}

extern "C" void kernel_launch(void* const* d_in, const int* in_sizes, int n_in,
                              void* d_out, int out_size, void* d_ws, size_t ws_size,
                              hipStream_t stream) {
    const float* x  = (const float*)d_in[0];
    const float* Wk = (const float*)d_in[1];
    const float* bk = (const float*)d_in[2];
    const float* Wq = (const float*)d_in[3];
    const float* bq = (const float*)d_in[4];
    const float* Wv = (const float*)d_in[5];
    const float* bv = (const float*)d_in[6];
    const float* Wo = (const float*)d_in[7];
    const float* bo = (const float*)d_in[8];
    float* out = (float*)d_out;

    char* ws = (char*)d_ws;
    unsigned short* xb  = (unsigned short*)(ws);                    // 8MB
    unsigned short* wkb = (unsigned short*)(ws + ((size_t)8  << 20));
    unsigned short* wqb = (unsigned short*)(ws + ((size_t)10 << 20));
    unsigned short* wvb = (unsigned short*)(ws + ((size_t)12 << 20));
    unsigned short* wob = (unsigned short*)(ws + ((size_t)14 << 20));
    unsigned short* qb  = (unsigned short*)(ws + ((size_t)16 << 20)); // [B,H,T,D]
    unsigned short* kb  = (unsigned short*)(ws + ((size_t)24 << 20)); // [B,H,T,D]
    unsigned short* vtb = (unsigned short*)(ws + ((size_t)32 << 20)); // [B,H,D,T]
    unsigned short* yb  = (unsigned short*)(ws + ((size_t)40 << 20)); // [B*T,C]

    cvt_all<<<dim3(8192), dim3(256), 0, stream>>>(
        x, Wk, Wq, Wv, Wo, xb, wkb, wqb, wvb, wob);

    gemm_qkv<<<dim3(768), dim3(256), 0, stream>>>(xb, wkb, wqb, wvb, bk, bq, bv, kb, qb, vtb);

    flash_attn<<<dim3(1024), dim3(256), 0, stream>>>(qb, kb, vtb, yb);

    gemm_out<<<dim3(512), dim3(256), 0, stream>>>(yb, wob, bo, out);
}